// Round 15
// baseline (220.792 us; speedup 1.0000x reference)
//
#include <hip/hip_runtime.h>

typedef __bf16 bf16x8 __attribute__((ext_vector_type(8)));
typedef float f32x4 __attribute__((ext_vector_type(4)));

#define Bdim 8192
#define Nn 36
#define Mrows 144            // 4 batches x 36 rows, packed (no pads)
#define Cc 128
#define EPSf 1e-4f

// ---- d_ws layout (ushort elements): qk hi/lo split, v/proj single-bf16 ----
#define WS_QK_HI 0
#define WS_QK_LO 32768
#define WS_V_HI  65536
#define WS_P_HI  81920

// ---- LDS map (bytes). Aliased by lifetime:
//  R1 0..73727      : PH [144][256B] swz15, PL [144][256B]      (A -> B)
//                     after B: KT [128][202]ush (0..51711), KV [4][8][16][16]ush (51712..68095)
//  R2 73728..110591 : XH [144][256B] swz15 (A -> B) ; then QH/O [144][256B] (C -> G)
//  R3 110592..162303: VT [128][202]ush                           (C -> D)
#define OFF_PH   0
#define OFF_PL   36864
#define OFF_KT   0
#define OFF_KV   51712
#define OFF_XH   73728
#define OFF_QO   73728
#define OFF_VT   110592
#define OFF_MASK 162304      // f32 [144] (per global row)
#define OFF_INN  162880      // f32 [4]
#define LDS_BYTES 162896

__device__ inline uint bfh(float f) {
    __bf16 h = (__bf16)f;
    return (uint)(*(const ushort*)&h);
}
__device__ inline uint bfl(float f) {
    float hf = (float)((__bf16)f);
    __bf16 l = (__bf16)(f - hf);
    return (uint)(*(const ushort*)&l);
}
__device__ inline uint pk2h(float a, float b) { return bfh(a) | (bfh(b) << 16); }
__device__ inline uint pk2l(float a, float b) { return bfl(a) | (bfl(b) << 16); }

union U8 { bf16x8 v; uint u[4]; };

// row (0..143) -> batch via magic div by 36 (exact for row < 1820)
__device__ __forceinline__ int rdiv36(int row) { return (row * 1821) >> 16; }

// ---------------- pre-kernel: weights -> frag-ordered bf16 in ws ----------------
__global__ __launch_bounds__(256)
void prep_frags(const float* __restrict__ qk_w, const float* __restrict__ v_w,
                const float* __restrict__ proj_w, ushort* __restrict__ ws)
{
    int e = blockIdx.x * 256 + threadIdx.x;          // 0..65535
    const float* W; int N; int idx; int hi_off; int lo_off;
    if (e < 32768)      { W = qk_w;   N = 256; hi_off = WS_QK_HI; lo_off = WS_QK_LO; idx = e; }
    else if (e < 49152) { W = v_w;    N = 128; hi_off = WS_V_HI;  lo_off = -1;       idx = e - 32768; }
    else                { W = proj_w; N = 128; hi_off = WS_P_HI;  lo_off = -1;       idx = e - 49152; }
    int j    = idx & 7;
    int lane = (idx >> 3) & 63;
    int ks   = (idx >> 9) & 3;
    int ct   = idx >> 11;
    int col  = ct * 16 + (lane & 15);
    int k    = ks * 32 + (lane >> 4) * 8 + j;
    float v  = W[k * N + col];
    ws[hi_off + idx] = (ushort)bfh(v);
    if (lo_off >= 0) ws[lo_off + idx] = (ushort)bfl(v);
}

// ------- main: one block (8 waves) = 4 batches, batched-M GEMM phases -------
__global__ __launch_bounds__(512, 2)
void fla_mfma(const float* __restrict__ x, const float* __restrict__ pos,
              const float* __restrict__ mask, const float* __restrict__ qk_b,
              const float* __restrict__ v_b, const float* __restrict__ proj_b,
              const int* __restrict__ vox, const ushort* __restrict__ ws,
              float* __restrict__ out)
{
    __shared__ __align__(16) char lds[LDS_BYTES];
    const int t = threadIdx.x;
    const int lane = t & 63;
    const int wv = t >> 6;                           // 8 waves
    const int  rsel = lane & 15;
    const int  grp  = lane >> 4;
    const uint kgrp = (uint)grp * 8u;
    const uint sw   = ((uint)rsel) << 4;             // row&15 swizzle on frag reads
    const int base4 = blockIdx.x * 4;                // 4 batches per block

    // =============== Phase A: stage 4 batches (144 packed rows) ===============
    {
        const float* xg = x + (size_t)base4 * (Nn * Cc);
        const float* pg = pos + (size_t)base4 * (Nn * Cc);
        #pragma unroll
        for (int it = 0; it < 9; ++it) {
            int idx = t + it * 512;                  // 144 rows x 32 float4 = 4608
            int n = idx >> 5;
            int c4 = (idx & 31) << 2;
            float4 xv = *(const float4*)(xg + n * Cc + c4);
            float4 pv = *(const float4*)(pg + n * Cc + c4);
            float s0 = xv.x + pv.x, s1 = xv.y + pv.y;
            float s2 = xv.z + pv.z, s3 = xv.w + pv.w;
            uint ba = (uint)n * 256u + (((uint)(c4 * 2)) ^ (((uint)n & 15u) << 4));
            *(uint2*)(lds + OFF_XH + ba) = make_uint2(pk2h(xv.x, xv.y), pk2h(xv.z, xv.w));
            *(uint2*)(lds + OFF_PH + ba) = make_uint2(pk2h(s0, s1), pk2h(s2, s3));
            *(uint2*)(lds + OFF_PL + ba) = make_uint2(pk2l(s0, s1), pk2l(s2, s3));
        }
        if (t < Mrows) {
            int b = rdiv36(t), rl = t - b * 36;
            ((float*)(lds + OFF_MASK))[t] = mask[(size_t)(base4 + b) * Nn + rl];
        }
        if (wv < 4) {                                // inn[b=wv] via butterfly
            float s = (lane < Nn) ? mask[(size_t)(base4 + wv) * Nn + lane] : 0.f;
            s += __shfl_xor(s, 1);  s += __shfl_xor(s, 2);
            s += __shfl_xor(s, 4);  s += __shfl_xor(s, 8);
            s += __shfl_xor(s, 16); s += __shfl_xor(s, 32);
            if (lane == 0) ((float*)(lds + OFF_INN))[wv] = 1.f / (s + EPSf);
        }
    }
    __syncthreads();

    // =============== Phase B: qk (split-bf16, 2 N-tiles/wave) + v (1 N-tile) ===============
    f32x4 accQ[9][2];
    f32x4 accV[9];
    #pragma unroll
    for (int m = 0; m < 9; ++m) {
        accQ[m][0] = (f32x4){0.f, 0.f, 0.f, 0.f};
        accQ[m][1] = (f32x4){0.f, 0.f, 0.f, 0.f};
        accV[m]    = (f32x4){0.f, 0.f, 0.f, 0.f};
    }
    #pragma unroll
    for (int ks = 0; ks < 4; ++ks) {
        uint ka = (((uint)(ks * 32) + kgrp) * 2u) ^ sw;
        int f0 = (((wv * 2 + 0) * 4 + ks) * 64 + lane) * 8;
        int f1 = (((wv * 2 + 1) * 4 + ks) * 64 + lane) * 8;
        bf16x8 bh0 = *(const bf16x8*)(ws + WS_QK_HI + f0);
        bf16x8 bl0 = *(const bf16x8*)(ws + WS_QK_LO + f0);
        bf16x8 bh1 = *(const bf16x8*)(ws + WS_QK_HI + f1);
        bf16x8 bl1 = *(const bf16x8*)(ws + WS_QK_LO + f1);
        #pragma unroll
        for (int m = 0; m < 9; ++m) {
            uint ba = (uint)(m * 16 + rsel) * 256u + ka;
            bf16x8 ph = *(const bf16x8*)(lds + OFF_PH + ba);
            bf16x8 pl = *(const bf16x8*)(lds + OFF_PL + ba);
            accQ[m][0] = __builtin_amdgcn_mfma_f32_16x16x32_bf16(ph, bh0, accQ[m][0], 0, 0, 0);
            accQ[m][0] = __builtin_amdgcn_mfma_f32_16x16x32_bf16(ph, bl0, accQ[m][0], 0, 0, 0);
            accQ[m][0] = __builtin_amdgcn_mfma_f32_16x16x32_bf16(pl, bh0, accQ[m][0], 0, 0, 0);
            accQ[m][1] = __builtin_amdgcn_mfma_f32_16x16x32_bf16(ph, bh1, accQ[m][1], 0, 0, 0);
            accQ[m][1] = __builtin_amdgcn_mfma_f32_16x16x32_bf16(ph, bl1, accQ[m][1], 0, 0, 0);
            accQ[m][1] = __builtin_amdgcn_mfma_f32_16x16x32_bf16(pl, bh1, accQ[m][1], 0, 0, 0);
        }
    }
    #pragma unroll
    for (int ks = 0; ks < 4; ++ks) {
        uint ka = (((uint)(ks * 32) + kgrp) * 2u) ^ sw;
        int fv = ((wv * 4 + ks) * 64 + lane) * 8;
        bf16x8 bv = *(const bf16x8*)(ws + WS_V_HI + fv);
        #pragma unroll
        for (int m = 0; m < 9; ++m) {
            uint ba = (uint)(m * 16 + rsel) * 256u + ka;
            bf16x8 xh = *(const bf16x8*)(lds + OFF_XH + ba);
            accV[m] = __builtin_amdgcn_mfma_f32_16x16x32_bf16(xh, bv, accV[m], 0, 0, 0);
        }
    }
    __syncthreads();   // staging dead; C overwrites R1/R2/R3

    // =============== Phase C: epilogues -> VT, QH(raw q3), KT(raw k3) ===============
    {
        const float* sM = (const float*)(lds + OFF_MASK);
        {   // v: +bias -> VT[d=col][b*50+rl] (4-row runs stay in one batch: 36 % 4 == 0)
            int colv = wv * 16 + rsel;
            float vb = v_b[colv];
            #pragma unroll
            for (int m = 0; m < 9; ++m) {
                int row0 = m * 16 + grp * 4;
                int b = rdiv36(row0), rl = row0 - b * 36;
                float a0 = accV[m][0] + vb, a1 = accV[m][1] + vb;
                float a2 = accV[m][2] + vb, a3 = accV[m][3] + vb;
                uint addr = OFF_VT + (uint)(colv * 202 + b * 50 + rl) * 2u;
                *(uint2*)(lds + addr) = make_uint2(pk2h(a0, a1), pk2h(a2, a3));
            }
        }
        if (wv < 4) {       // q: +bias, cube -> QH (all 144 rows real; no guard)
            #pragma unroll
            for (int ci = 0; ci < 2; ++ci) {
                int colq = (wv * 2 + ci) * 16 + rsel;
                float qb = qk_b[colq];
                uint cb2 = (uint)(colq * 2);
                #pragma unroll
                for (int m = 0; m < 9; ++m) {
                    #pragma unroll
                    for (int r = 0; r < 4; ++r) {
                        int row = m * 16 + grp * 4 + r;
                        float q1 = accQ[m][ci][r] + qb;
                        float q3 = q1 * q1 * q1;
                        uint ba = (uint)row * 256u + (cb2 ^ (((uint)row & 15u) << 4));
                        *(ushort*)(lds + OFF_QO + ba) = (ushort)bfh(q3);
                    }
                }
            }
        } else {            // k: +bias, *mask, cube -> KT[c][b*50+rl]
            #pragma unroll
            for (int ci = 0; ci < 2; ++ci) {
                int colk = ((wv - 4) * 2 + ci) * 16 + rsel;
                float kb = qk_b[Cc + colk];
                #pragma unroll
                for (int m = 0; m < 9; ++m) {
                    int row0 = m * 16 + grp * 4;
                    int b = rdiv36(row0), rl = row0 - b * 36;
                    float k3v[4];
                    #pragma unroll
                    for (int r = 0; r < 4; ++r) {
                        float k1 = (accQ[m][ci][r] + kb) * sM[row0 + r];
                        k3v[r] = k1 * k1 * k1;
                    }
                    uint addr = OFF_KT + (uint)(colk * 202 + b * 50 + rl) * 2u;
                    *(uint2*)(lds + addr) = make_uint2(pk2h(k3v[0], k3v[1]), pk2h(k3v[2], k3v[3]));
                }
            }
        }
        // zero KT/VT pad slots n = b*50 + 36..49 (D's MFMA reads n 0..47)
        {
            int col = t >> 2, b = t & 3;
            uint pbase = (uint)(col * 202 + b * 50 + 36) * 2u;
            #pragma unroll
            for (int j = 0; j < 7; ++j) {
                *(uint*)(lds + OFF_KT + pbase + j * 4) = 0u;
                *(uint*)(lds + OFF_VT + pbase + j * 4) = 0u;
            }
        }
    }
    __syncthreads();

    // =============== Phase D: kv-hat per (b, head=wv) -> KV (wave-private) ===============
    {
        int col16 = wv * 16 + rsel;                  // c (A-row) and d (B-col)
        #pragma unroll
        for (int b = 0; b < 4; ++b) {
            uint a0 = OFF_KT + (uint)(col16 * 202 + b * 50 + grp * 8) * 2u;
            uint b0 = OFF_VT + (uint)(col16 * 202 + b * 50 + grp * 8) * 2u;
            bf16x8 kA0 = *(const bf16x8*)(lds + a0);
            bf16x8 vB0 = *(const bf16x8*)(lds + b0);
            U8 kA1, vB1;
            kA1.u[0] = kA1.u[1] = kA1.u[2] = kA1.u[3] = 0u;
            vB1.u[0] = vB1.u[1] = vB1.u[2] = vB1.u[3] = 0u;
            if (grp < 2) {                           // n = 32 + grp*8 .. +7
                kA1.v = *(const bf16x8*)(lds + a0 + 64);
                vB1.v = *(const bf16x8*)(lds + b0 + 64);
            }
            float s = 0.f;
            #pragma unroll
            for (int j = 0; j < 8; ++j) { float q = (float)kA0[j]; s += q * q; }
            #pragma unroll
            for (int j = 0; j < 8; ++j) { float q = (float)kA1.v[j]; s += q * q; }
            s += __shfl_xor(s, 16);
            s += __shfl_xor(s, 32);
            float invkn = 1.f / (EPSf + sqrtf(s));

            f32x4 kvacc = (f32x4){0.f, 0.f, 0.f, 0.f};
            kvacc = __builtin_amdgcn_mfma_f32_16x16x32_bf16(kA0, vB0, kvacc, 0, 0, 0);
            kvacc = __builtin_amdgcn_mfma_f32_16x16x32_bf16(kA1.v, vB1.v, kvacc, 0, 0, 0);

            float f0 = __shfl(invkn, grp * 4 + 0);
            float f1 = __shfl(invkn, grp * 4 + 1);
            float f2 = __shfl(invkn, grp * 4 + 2);
            float f3 = __shfl(invkn, grp * 4 + 3);
            // KV[b][wv][d=rsel][c=grp*4..+3]
            uint addr = OFF_KV + (uint)((((b * 8 + wv) * 16 + rsel) * 16) + grp * 4) * 2u;
            *(uint2*)(lds + addr) =
                make_uint2(pk2h(kvacc[0] * f0, kvacc[1] * f1), pk2h(kvacc[2] * f2, kvacc[3] * f3));
        }
    }
    // no barrier: KV is produced and consumed by the same wave (head wv)

    // =============== Phase E: out = invn*inn * (q3 @ kv-hat) -> O over QH (own cols) ======
    {
        #pragma unroll
        for (int b = 0; b < 4; ++b) {
            U8 bkv;
            bkv.u[0] = bkv.u[1] = bkv.u[2] = bkv.u[3] = 0u;
            if (grp < 2)                              // c = grp*8 + j at d = rsel
                bkv.v = *(const bf16x8*)(lds + OFF_KV +
                          (uint)((((b * 8 + wv) * 16 + rsel) * 16) + grp * 8) * 2u);
            float inn = ((const float*)(lds + OFF_INN))[b];
            f32x4 oacc[3];
            float invn[3];
            #pragma unroll
            for (int rt = 0; rt < 3; ++rt) {
                int rloc = rt * 16 + rsel;
                U8 aq;
                aq.u[0] = aq.u[1] = aq.u[2] = aq.u[3] = 0u;
                if (grp < 2 && rloc < Nn) {
                    int rg = b * 36 + rloc;
                    uint ba = (uint)rg * 256u +
                              (((uint)(wv * 32 + grp * 16)) ^ (((uint)rg & 15u) << 4));
                    aq.v = *(const bf16x8*)(lds + OFF_QO + ba);
                }
                float s = 0.f;
                #pragma unroll
                for (int j = 0; j < 8; ++j) { float q = (float)aq.v[j]; s += q * q; }
                s += __shfl_xor(s, 16);               // lanes 0..15 hold full row sum
                invn[rt] = 1.f / (EPSf + sqrtf(s));
                f32x4 o = (f32x4){0.f, 0.f, 0.f, 0.f};
                o = __builtin_amdgcn_mfma_f32_16x16x32_bf16(aq.v, bkv.v, o, 0, 0, 0);
                oacc[rt] = o;
            }
            #pragma unroll
            for (int rt = 0; rt < 3; ++rt) {
                #pragma unroll
                for (int r = 0; r < 4; ++r) {
                    int rr = grp * 4 + r;
                    int rloc = rt * 16 + rr;
                    if (rloc < Nn) {
                        int rg = b * 36 + rloc;
                        float fac = __shfl(invn[rt], rr) * inn;
                        float val = oacc[rt][r] * fac;
                        uint ba = (uint)rg * 256u +
                                  (((uint)((wv * 16 + rsel) * 2)) ^ (((uint)rg & 15u) << 4));
                        *(ushort*)(lds + OFF_QO + ba) = (ushort)bfh(val);
                    }
                }
            }
        }
    }
    __syncthreads();                                  // O complete (all 144 rows, all cols)

    // =============== Phase G: proj GEMM (1 N-tile/wave, M=144) + voxel scatter ============
    {
        f32x4 accP[9];
        #pragma unroll
        for (int m = 0; m < 9; ++m) accP[m] = (f32x4){0.f, 0.f, 0.f, 0.f};
        #pragma unroll
        for (int ks = 0; ks < 4; ++ks) {
            uint ka = (((uint)(ks * 32) + kgrp) * 2u) ^ sw;
            int fp = ((wv * 4 + ks) * 64 + lane) * 8;
            bf16x8 bp = *(const bf16x8*)(ws + WS_P_HI + fp);
            #pragma unroll
            for (int m = 0; m < 9; ++m) {
                uint ba = (uint)(m * 16 + rsel) * 256u + ka;
                bf16x8 oa = *(const bf16x8*)(lds + OFF_QO + ba);
                accP[m] = __builtin_amdgcn_mfma_f32_16x16x32_bf16(oa, bp, accP[m], 0, 0, 0);
            }
        }
        int col = wv * 16 + rsel;
        float pb = proj_b[col];
        #pragma unroll
        for (int m = 0; m < 9; ++m) {
            int row0 = m * 16 + grp * 4;
            int b = rdiv36(row0), rl = row0 - b * 36;
            const int* voxb = vox + (size_t)(base4 + b) * Nn + rl;
            #pragma unroll
            for (int r = 0; r < 4; ++r) {
                int vrow = voxb[r];
                out[(size_t)vrow * Cc + col] = accP[m][r] + pb;
            }
        }
    }
}

extern "C" void kernel_launch(void* const* d_in, const int* in_sizes, int n_in,
                              void* d_out, int out_size, void* d_ws, size_t ws_size,
                              hipStream_t stream) {
    (void)in_sizes; (void)n_in; (void)out_size; (void)ws_size;
    const float* x      = (const float*)d_in[0];
    const float* pos    = (const float*)d_in[1];
    const float* mask   = (const float*)d_in[2];
    const float* qk_w   = (const float*)d_in[3];
    const float* qk_b   = (const float*)d_in[4];
    const float* v_w    = (const float*)d_in[5];
    const float* v_b    = (const float*)d_in[6];
    const float* proj_w = (const float*)d_in[7];
    const float* proj_b = (const float*)d_in[8];
    // d_in[9] = coords (unused)
    const int*   vox    = (const int*)d_in[10];
    ushort* ws = (ushort*)d_ws;            // 192 KiB scratch used
    float* outp = (float*)d_out;

    hipLaunchKernelGGL(prep_frags, dim3(256), dim3(256), 0, stream, qk_w, v_w, proj_w, ws);
    hipLaunchKernelGGL(fla_mfma, dim3(Bdim / 4), dim3(512), 0, stream,
                       x, pos, mask, qk_b, v_b, proj_b, vox, ws, outp);
}